// Round 3
// baseline (437.801 us; speedup 1.0000x reference)
//
#include <hip/hip_runtime.h>
#include <hip/hip_bf16.h>
#include <math.h>

#define DEVI static __device__ __forceinline__

typedef __attribute__((ext_vector_type(4))) float f32x4;
typedef __attribute__((ext_vector_type(8))) short bf16x8;
typedef __attribute__((ext_vector_type(4))) short bf16x4;

constexpr int Bc = 4, Lc = 2048, Sc = 2048, Dc = 1024, Hc = 8, Ec = 128, UVc = 128;
constexpr int HEc = Hc * Ec;   // 1024
constexpr int BLc = Bc * Lc;   // 8192

DEVI unsigned f2bf_bits(float f) {
  unsigned u = __builtin_bit_cast(unsigned, f);
  return (u + 0x7FFFu + ((u >> 16) & 1u)) >> 16;
}
DEVI short f2bf(float f) { return (short)f2bf_bits(f); }
DEVI float bf2f(short s) {
  return __builtin_bit_cast(float, (unsigned)((unsigned short)s) << 16);
}
DEVI float gelu_f(float x) { return 0.5f * x * (1.0f + erff(x * 0.7071067811865476f)); }

DEVI void gload16(const void* gsrc, void* ldst) {
  __builtin_amdgcn_global_load_lds(
      (const __attribute__((address_space(1))) unsigned*)gsrc,
      (__attribute__((address_space(3))) unsigned*)(ldst), 16, 0, 0);
}

DEVI f32x4 mfma16(bf16x8 a, bf16x8 b, f32x4 c) {
  return __builtin_amdgcn_mfma_f32_16x16x32_bf16(a, b, c, 0, 0, 0);
}

// ---------------- prep: 4 weight transposes f32[K][N] -> bf16 WT[N][K] ----------------
__global__ void wt_trans_kernel(const float* __restrict__ W0, const float* __restrict__ W1,
                                const float* __restrict__ W2, const float* __restrict__ W3,
                                short* __restrict__ T0, short* __restrict__ T1,
                                short* __restrict__ T2, short* __restrict__ T3) {
  __shared__ float t[32][33];
  const float* Ws[4] = {W0, W1, W2, W3};
  short* Ts[4] = {T0, T1, T2, T3};
  const float* W = Ws[blockIdx.z];
  short* WT = Ts[blockIdx.z];
  int tx = threadIdx.x, ty = threadIdx.y;
  int n0 = blockIdx.x * 32, k0 = blockIdx.y * 32;
#pragma unroll
  for (int i = 0; i < 4; i++) {
    int r = ty + i * 8;
    t[r][tx] = W[(size_t)(k0 + r) * 1024 + n0 + tx];
  }
  __syncthreads();
#pragma unroll
  for (int i = 0; i < 4; i++) {
    int r = ty + i * 8;
    WT[(size_t)(n0 + r) * 1024 + k0 + tx] = f2bf(t[tx][r]);
  }
}

// ---------------- prep: packed rope table [2048][512] of (cos,sin) ----------------
__global__ void rope_cs_kernel(float2* __restrict__ cs) {
  int idx = blockIdx.x * 256 + threadIdx.x;  // 1M
  int t = idx >> 9, i = idx & 511;
  float inv = expf((float)i * (-9.210340371976184f / 512.0f));  // 10000^(-i/512)
  float sv, cv;
  sincosf((float)t * inv, &sv, &cv);
  cs[idx] = make_float2(cv, sv);
}

// ---------------- GEMM: C = epi(A @ W + bias); A f32 or bf16 [M][K], W as WT[N][K] bf16 ----
// 128x128 tile, BK=32, dbuf swizzled LDS. B via global_load_lds; A either gload16 (bf16)
// or f32 reg-stage + convert + ds_write. EPI: 0 = f32+bias, 1 = gelu->bf16, 2 = rope q/k.
template <bool AF32, int EPI>
__global__ __launch_bounds__(256, 2) void gemm_kernel(
    const void* __restrict__ Aptr, const short* __restrict__ BT,
    const float* __restrict__ bias, void* __restrict__ Cptr,
    const float2* __restrict__ cstab,
    const float* __restrict__ qg, const float* __restrict__ qb,
    const float* __restrict__ kg, const float* __restrict__ kb,
    short* __restrict__ qout, short* __restrict__ kout, int M, int N, int K) {
  __shared__ char smem[32768];
  const int tid = threadIdx.x;
  const int wave = tid >> 6, lane = tid & 63;
  const int lquad = lane >> 4, l15 = lane & 15;
  const int m0 = blockIdx.x * 128, n0 = blockIdx.y * 128;
  const int wr = wave >> 1, wc = wave & 1;
  f32x4 acc[4][4] = {};

  // gload16 staging addrs (B always; A when bf16)
  const int q0 = tid * 16, q1 = tid * 16 + 4096;
  const int r0 = q0 >> 6, o0 = (q0 & 63) ^ ((r0 & 3) << 4);
  const int r1 = q1 >> 6, o1 = (q1 & 63) ^ ((r1 & 3) << 4);
  const short* b0 = BT + (size_t)(n0 + r0) * K + (o0 >> 1);
  const short* b1 = BT + (size_t)(n0 + r1) * K + (o1 >> 1);
  const short* a0 = nullptr;
  const short* a1 = nullptr;
  const float* asrc = nullptr;
  int arow = 0, ao0 = 0, ao1 = 0;
  if (AF32) {
    arow = tid >> 1;
    int ahalf = tid & 1, asw = (arow & 3) << 4;
    asrc = (const float*)Aptr + (size_t)(m0 + arow) * K + ahalf * 16;
    ao0 = (ahalf * 32) ^ asw;
    ao1 = (ahalf * 32 + 16) ^ asw;
  } else {
    a0 = (const short*)Aptr + (size_t)(m0 + r0) * K + (o0 >> 1);
    a1 = (const short*)Aptr + (size_t)(m0 + r1) * K + (o1 >> 1);
  }
  float4 fa0, fa1, fa2, fa3;

#define LOAD_A_F32(kt)                                \
  {                                                   \
    const float* s_ = asrc + (kt);                    \
    fa0 = *reinterpret_cast<const float4*>(s_);       \
    fa1 = *reinterpret_cast<const float4*>(s_ + 4);   \
    fa2 = *reinterpret_cast<const float4*>(s_ + 8);   \
    fa3 = *reinterpret_cast<const float4*>(s_ + 12);  \
  }
#define WRITE_A_F32(buf)                                 \
  {                                                      \
    char* d_ = smem + (buf)*8192 + arow * 64;            \
    uint4 lo_, hi_;                                      \
    lo_.x = f2bf_bits(fa0.x) | (f2bf_bits(fa0.y) << 16); \
    lo_.y = f2bf_bits(fa0.z) | (f2bf_bits(fa0.w) << 16); \
    lo_.z = f2bf_bits(fa1.x) | (f2bf_bits(fa1.y) << 16); \
    lo_.w = f2bf_bits(fa1.z) | (f2bf_bits(fa1.w) << 16); \
    hi_.x = f2bf_bits(fa2.x) | (f2bf_bits(fa2.y) << 16); \
    hi_.y = f2bf_bits(fa2.z) | (f2bf_bits(fa2.w) << 16); \
    hi_.z = f2bf_bits(fa3.x) | (f2bf_bits(fa3.y) << 16); \
    hi_.w = f2bf_bits(fa3.z) | (f2bf_bits(fa3.w) << 16); \
    *reinterpret_cast<uint4*>(d_ + ao0) = lo_;           \
    *reinterpret_cast<uint4*>(d_ + ao1) = hi_;           \
  }
#define STAGE_B(buf, kt)                     \
  {                                          \
    char* Bs_ = smem + 16384 + (buf)*8192;   \
    gload16(b0 + (kt), Bs_ + q0);            \
    gload16(b1 + (kt), Bs_ + q1);            \
  }
#define STAGE_A_BF(buf, kt)                  \
  {                                          \
    char* As_ = smem + (buf)*8192;           \
    gload16(a0 + (kt), As_ + q0);            \
    gload16(a1 + (kt), As_ + q1);            \
  }

  // prologue
  if (AF32) {
    LOAD_A_F32(0);
    WRITE_A_F32(0);
  } else {
    STAGE_A_BF(0, 0);
  }
  STAGE_B(0, 0);
  asm volatile("s_waitcnt vmcnt(0) lgkmcnt(0)" ::: "memory");
  __builtin_amdgcn_s_barrier();

  const int NT = K >> 5;
  for (int t = 0; t < NT; t++) {
    const int cur = t & 1;
    const bool pf = (t + 1 < NT);
    if (pf) {
      if (AF32) LOAD_A_F32((t + 1) * 32) else STAGE_A_BF(cur ^ 1, (t + 1) * 32);
      STAGE_B(cur ^ 1, (t + 1) * 32);
    }
    __builtin_amdgcn_sched_barrier(0);
    const char* As_ = smem + cur * 8192;
    const char* Bs_ = smem + 16384 + cur * 8192;
    const int ko = lquad * 16;
    bf16x8 a[4], b[4];
#pragma unroll
    for (int f = 0; f < 4; f++) {
      int ra = wr * 64 + f * 16 + l15;
      a[f] = *reinterpret_cast<const bf16x8*>(As_ + ra * 64 + (ko ^ ((ra & 3) << 4)));
      int rb = wc * 64 + f * 16 + l15;
      b[f] = *reinterpret_cast<const bf16x8*>(Bs_ + rb * 64 + (ko ^ ((rb & 3) << 4)));
    }
#pragma unroll
    for (int mf = 0; mf < 4; mf++)
#pragma unroll
      for (int nf = 0; nf < 4; nf++)
        acc[mf][nf] = mfma16(a[mf], b[nf], acc[mf][nf]);
    if (AF32 && pf) WRITE_A_F32(cur ^ 1);
    asm volatile("s_waitcnt vmcnt(0) lgkmcnt(0)" ::: "memory");
    __builtin_amdgcn_sched_barrier(0);
    __builtin_amdgcn_s_barrier();
  }
#undef LOAD_A_F32
#undef WRITE_A_F32
#undef STAGE_B
#undef STAGE_A_BF

#pragma unroll
  for (int mf = 0; mf < 4; mf++) {
#pragma unroll
    for (int nf = 0; nf < 4; nf++) {
      const int mrow = m0 + wr * 64 + mf * 16 + 4 * lquad;
      const int ncol = n0 + wc * 64 + nf * 16 + l15;
      const float bval = bias[ncol];
      if constexpr (EPI == 2) {
        const int e7 = ncol & 127;
        const float QG = qg[e7], QB = qb[e7], KG = kg[e7], KB = kb[e7];
        const int p = ncol >> 1;
        const float sgn = (ncol & 1) ? 1.0f : -1.0f;
#pragma unroll
        for (int r = 0; r < 4; r++) {
          const int m = mrow + r;
          const int tt = m & 2047;
          float2 cs = cstab[(size_t)tt * 512 + p];
          float g = gelu_f(acc[mf][nf][r] + bval);
          float qv = g * QG + QB, kv = g * KG + KB;
          float pq = __shfl_xor(qv, 1), pk = __shfl_xor(kv, 1);
          qout[(size_t)m * N + ncol] = f2bf(qv * cs.x + sgn * pq * cs.y);
          kout[(size_t)m * N + ncol] = f2bf(kv * cs.x + sgn * pk * cs.y);
        }
      } else if constexpr (EPI == 1) {
#pragma unroll
        for (int r = 0; r < 4; r++)
          ((short*)Cptr)[(size_t)(mrow + r) * N + ncol] = f2bf(gelu_f(acc[mf][nf][r] + bval));
      } else {
#pragma unroll
        for (int r = 0; r < 4; r++)
          ((float*)Cptr)[(size_t)(mrow + r) * N + ncol] = acc[mf][nf][r] + bval;
      }
    }
  }
}

// ---------------- v transpose: [B][S][H][UV] -> [B][H][UV][S] (bf16) ----------------
__global__ void vtrans_kernel(const short* __restrict__ v, short* __restrict__ vT) {
  __shared__ short t[32][33];
  int bh = blockIdx.z;
  int b = bh >> 3, h = bh & 7;
  int s0 = blockIdx.x * 32, d0 = blockIdx.y * 32;
  int tx = threadIdx.x, ty = threadIdx.y;
#pragma unroll
  for (int i = 0; i < 4; i++) {
    int s = ty + i * 8;
    t[s][tx] = v[(((size_t)b * Sc + s0 + s) * Hc + h) * UVc + d0 + tx];
  }
  __syncthreads();
#pragma unroll
  for (int i = 0; i < 4; i++) {
    int d = ty + i * 8;
    vT[((size_t)bh * UVc + d0 + d) * Sc + s0 + tx] = t[tx][d];
  }
}

// ---------------- attention ----------------
// grid 512 = 8 XCD * 4 bh * 16 lblk; per block 128 L-rows; s-tiles of 64.
// Pass A: 4-deep K pipeline (4x16KB bufs, counted vmcnt). Pass B: dbuf K+V.
__global__ __launch_bounds__(256, 2) void attn_kernel(
    const short* __restrict__ qs, const short* __restrict__ ks,
    const short* __restrict__ vT, const short* __restrict__ up,
    float* __restrict__ attn_out, short* __restrict__ gate) {
  __shared__ char smem[65536];
  const int bid = blockIdx.x;
  const int xcd = bid & 7, jj = bid >> 3;
  const int bh = xcd * 4 + (jj >> 4);
  const int lblk = jj & 15;
  const int b = bh >> 3, h = bh & 7;
  const int l0 = lblk * 128;
  const int tid = threadIdx.x;
  const int wave = tid >> 6, lane = tid & 63;
  const int lquad = lane >> 4, l15 = lane & 15;
  const float scale = 0.08838834764831845f;  // 1/sqrt(128)

  // staging: K tile [64][128] (256B rows), V tile [128][64] (128B rows); swizzle ^((row&7)<<4)
  const short* ksrc[4];
  const short* vsrc[4];
  int qdst[4];
#pragma unroll
  for (int i = 0; i < 4; i++) {
    int q = i * 4096 + tid * 16;
    qdst[i] = q;
    int row = q >> 8, off = (q & 255) ^ ((row & 7) << 4);
    ksrc[i] = ks + (((size_t)b * Sc + row) * Hc + h) * Ec + (off >> 1);
    int rv = q >> 7, ov = (q & 127) ^ ((rv & 7) << 4);
    vsrc[i] = vT + ((size_t)bh * UVc + rv) * Sc + (ov >> 1);
  }

#define STAGE_K(buf, s0)                                  \
  {                                                       \
    char* Kb_ = smem + (buf)*16384;                       \
    gload16(ksrc[0] + (size_t)(s0)*1024, Kb_ + qdst[0]);  \
    gload16(ksrc[1] + (size_t)(s0)*1024, Kb_ + qdst[1]);  \
    gload16(ksrc[2] + (size_t)(s0)*1024, Kb_ + qdst[2]);  \
    gload16(ksrc[3] + (size_t)(s0)*1024, Kb_ + qdst[3]);  \
  }
#define STAGE_V(buf, s0)                     \
  {                                          \
    char* Vb_ = smem + 32768 + (buf)*16384;  \
    gload16(vsrc[0] + (s0), Vb_ + qdst[0]);  \
    gload16(vsrc[1] + (s0), Vb_ + qdst[1]);  \
    gload16(vsrc[2] + (s0), Vb_ + qdst[2]);  \
    gload16(vsrc[3] + (s0), Vb_ + qdst[3]);  \
  }

  // Q fragments (B-operand, contiguous-k convention)
  bf16x8 qf[2][4];
#pragma unroll
  for (int cf = 0; cf < 2; cf++) {
    int lrow = l0 + wave * 32 + cf * 16 + l15;
    const short* qp = qs + (((size_t)b * Lc + lrow) * Hc + h) * Ec;
#pragma unroll
    for (int kt = 0; kt < 4; kt++)
      qf[cf][kt] = *reinterpret_cast<const bf16x8*>(qp + kt * 32 + lquad * 8);
  }
  __builtin_amdgcn_sched_barrier(0);  // pin Q loads (8 vm) before pipeline stages

#define QK_TILE(KBASE, d)                                                   \
  {                                                                         \
    const char* KB_ = (KBASE);                                              \
    _Pragma("unroll") for (int kt = 0; kt < 4; kt++) {                      \
      _Pragma("unroll") for (int sf = 0; sf < 4; sf++) {                    \
        int row = sf * 16 + l15;                                            \
        bf16x8 kf = *reinterpret_cast<const bf16x8*>(                       \
            KB_ + row * 256 + ((kt * 64 + lquad * 16) ^ ((row & 7) << 4))); \
        d[sf][0] = mfma16(kf, qf[0][kt], d[sf][0]);                         \
        d[sf][1] = mfma16(kf, qf[1][kt], d[sf][1]);                         \
      }                                                                     \
    }                                                                       \
  }

  // ---- pass A: row sums of exp(scale * scores), 4-buffer 3-ahead pipeline ----
  STAGE_K(0, 0);
  __builtin_amdgcn_sched_barrier(0);
  STAGE_K(1, 64);
  __builtin_amdgcn_sched_barrier(0);
  STAGE_K(2, 128);
  __builtin_amdgcn_sched_barrier(0);
  float rs0 = 0.f, rs1 = 0.f;
  for (int t = 0; t < 32; t++) {
    // per-wave outstanding: stages t,t+1,t+2 (4 vm each) + Q(8) at t=0
    if (t < 30)
      asm volatile("s_waitcnt vmcnt(8)" ::: "memory");
    else if (t == 30)
      asm volatile("s_waitcnt vmcnt(4)" ::: "memory");
    else
      asm volatile("s_waitcnt vmcnt(0)" ::: "memory");
    __builtin_amdgcn_sched_barrier(0);
    __builtin_amdgcn_s_barrier();
    f32x4 d[4][2] = {};
    QK_TILE(smem + (t & 3) * 16384, d);
#pragma unroll
    for (int sf = 0; sf < 4; sf++)
#pragma unroll
      for (int r = 0; r < 4; r++) {
        rs0 += __expf(scale * d[sf][0][r]);
        rs1 += __expf(scale * d[sf][1][r]);
      }
    asm volatile("s_waitcnt lgkmcnt(0)" ::: "memory");
    __builtin_amdgcn_sched_barrier(0);
    __builtin_amdgcn_s_barrier();
    if (t < 29) STAGE_K((t + 3) & 3, (t + 3) * 64);
  }
  rs0 += __shfl_xor(rs0, 16);
  rs0 += __shfl_xor(rs0, 32);
  rs1 += __shfl_xor(rs1, 16);
  rs1 += __shfl_xor(rs1, 32);
  const float rcp0 = 1.0f / rs0, rcp1 = 1.0f / rs1;

  // ---- pass B: recompute scores, write attn (nt, from regs), ctx^T = V^T @ P^T ----
  STAGE_K(0, 0);
  STAGE_V(0, 0);
  asm volatile("s_waitcnt vmcnt(0)" ::: "memory");
  __builtin_amdgcn_s_barrier();
  f32x4 ctx[8][2] = {};
  for (int t = 0; t < 32; t++) {
    const int cur = t & 1;
    const int s0 = t * 64;
    if (t < 31) {
      STAGE_K(cur ^ 1, s0 + 64);
      STAGE_V(cur ^ 1, s0 + 64);
    }
    __builtin_amdgcn_sched_barrier(0);
    f32x4 d[4][2] = {};
    QK_TILE(smem + cur * 16384, d);
#pragma unroll
    for (int sf = 0; sf < 4; sf++)
#pragma unroll
      for (int r = 0; r < 4; r++) {
        d[sf][0][r] = __expf(scale * d[sf][0][r]) * rcp0;
        d[sf][1][r] = __expf(scale * d[sf][1][r]) * rcp1;
      }
    // attn writes straight from D-registers (nontemporal: write-once stream)
#pragma unroll
    for (int cf = 0; cf < 2; cf++) {
      int lrow = l0 + wave * 32 + cf * 16 + l15;
      float* arow = attn_out + ((size_t)bh * Lc + lrow) * Sc + s0 + lquad * 4;
#pragma unroll
      for (int sf = 0; sf < 4; sf++)
        __builtin_nontemporal_store(d[sf][cf], reinterpret_cast<f32x4*>(arow + sf * 16));
    }
    // PV (P^T frags lane-local from d)
    const char* VB_ = smem + 32768 + cur * 16384;
#pragma unroll
    for (int c = 0; c < 2; c++) {
      bf16x8 pb0, pb1;
#pragma unroll
      for (int r = 0; r < 4; r++) {
        pb0[r] = f2bf(d[2 * c][0][r]);
        pb0[4 + r] = f2bf(d[2 * c + 1][0][r]);
        pb1[r] = f2bf(d[2 * c][1][r]);
        pb1[4 + r] = f2bf(d[2 * c + 1][1][r]);
      }
#pragma unroll
      for (int df = 0; df < 8; df++) {
        int dd = df * 16 + l15;
        int sw = (dd & 7) << 4;
        const char* vrow = VB_ + dd * 128;
        bf16x4 lo = *reinterpret_cast<const bf16x4*>(vrow + ((c * 64 + lquad * 8) ^ sw));
        bf16x4 hi = *reinterpret_cast<const bf16x4*>(vrow + ((c * 64 + 32 + lquad * 8) ^ sw));
        bf16x8 vf = __builtin_shufflevector(lo, hi, 0, 1, 2, 3, 4, 5, 6, 7);
        ctx[df][0] = mfma16(vf, pb0, ctx[df][0]);
        ctx[df][1] = mfma16(vf, pb1, ctx[df][1]);
      }
    }
    // drain prev stores + next-tile stage; leave this iter's 8 stores in flight
    asm volatile("s_waitcnt vmcnt(8) lgkmcnt(0)" ::: "memory");
    __builtin_amdgcn_sched_barrier(0);
    __builtin_amdgcn_s_barrier();
  }
#undef STAGE_K
#undef STAGE_V
#undef QK_TILE

  // ---- epilogue: gate = u_p * ctx, direct from regs ----
#pragma unroll
  for (int cf = 0; cf < 2; cf++) {
    int lrow = l0 + wave * 32 + cf * 16 + l15;
    size_t base = ((size_t)b * Lc + lrow) * HEc + h * UVc;
    const short* ub = up + base;
    short* gp = gate + base;
#pragma unroll
    for (int df = 0; df < 8; df++) {
      int doff = df * 16 + lquad * 4;
      bf16x4 uv = *reinterpret_cast<const bf16x4*>(ub + doff);
      bf16x4 gv;
#pragma unroll
      for (int r = 0; r < 4; r++)
        gv[r] = f2bf(bf2f(uv[r]) * ctx[df][cf][r]);
      *reinterpret_cast<bf16x4*>(gp + doff) = gv;
    }
  }
}

// ---------------- launch ----------------
extern "C" void kernel_launch(void* const* d_in, const int* in_sizes, int n_in,
                              void* d_out, int out_size, void* d_ws, size_t ws_size,
                              hipStream_t stream) {
  const float* u_in = (const float*)d_in[0];
  const float* qry = (const float*)d_in[1];
  // d_in[2] = keys : unused (use_aff shared qk projection)
  const float* vals = (const float*)d_in[3];
  const float* Wqk = (const float*)d_in[4];
  const float* bqk = (const float*)d_in[5];
  const float* Wv = (const float*)d_in[6];
  const float* bv = (const float*)d_in[7];
  const float* Wu = (const float*)d_in[8];
  const float* bu = (const float*)d_in[9];
  const float* Wo = (const float*)d_in[10];
  const float* bo = (const float*)d_in[11];
  const float* qg = (const float*)d_in[12];
  const float* qb = (const float*)d_in[13];
  const float* kg = (const float*)d_in[14];
  const float* kb = (const float*)d_in[15];

  char* w = (char*)d_ws;
  short* WT0 = (short*)w; w += (size_t)1024 * 1024 * 2;
  short* WT1 = (short*)w; w += (size_t)1024 * 1024 * 2;
  short* WT2 = (short*)w; w += (size_t)1024 * 1024 * 2;
  short* WT3 = (short*)w; w += (size_t)1024 * 1024 * 2;
  float2* cstab = (float2*)w; w += (size_t)2048 * 512 * 8;
  const size_t BUF = (size_t)BLc * HEc * 2;  // 16.78 MB
  short* qbf = (short*)w; w += BUF;
  short* kbf = (short*)w; w += BUF;
  short* vgl = (short*)w; w += BUF;
  short* vTb = (short*)w; w += BUF;
  short* upb = (short*)w; w += BUF;
  short* gtb = (short*)w; w += BUF;

  float* o_out = (float*)d_out;
  float* attn_out = o_out + (size_t)BLc * Dc;

  dim3 tb(32, 8);
  wt_trans_kernel<<<dim3(32, 32, 4), tb, 0, stream>>>(Wqk, Wv, Wu, Wo, WT0, WT1, WT2, WT3);
  rope_cs_kernel<<<4096, 256, 0, stream>>>(cstab);

  gemm_kernel<true, 2><<<dim3(64, 8), 256, 0, stream>>>(
      qry, WT0, bqk, nullptr, cstab, qg, qb, kg, kb, qbf, kbf, BLc, HEc, Dc);
  gemm_kernel<true, 1><<<dim3(64, 8), 256, 0, stream>>>(
      vals, WT1, bv, vgl, nullptr, nullptr, nullptr, nullptr, nullptr, nullptr, nullptr,
      BLc, HEc, Dc);
  vtrans_kernel<<<dim3(64, 4, 32), tb, 0, stream>>>(vgl, vTb);
  gemm_kernel<true, 1><<<dim3(64, 8), 256, 0, stream>>>(
      u_in, WT2, bu, upb, nullptr, nullptr, nullptr, nullptr, nullptr, nullptr, nullptr,
      BLc, HEc, Dc);
  attn_kernel<<<512, 256, 0, stream>>>(qbf, kbf, vTb, upb, attn_out, gtb);
  gemm_kernel<false, 0><<<dim3(64, 8), 256, 0, stream>>>(
      gtb, WT3, bo, o_out, nullptr, nullptr, nullptr, nullptr, nullptr, nullptr, nullptr,
      BLc, Dc, HEc);
}

// Round 4
// 389.560 us; speedup vs baseline: 1.1238x; 1.1238x over previous
//
#include <hip/hip_runtime.h>
#include <hip/hip_bf16.h>
#include <math.h>

#define DEVI static __device__ __forceinline__

typedef __attribute__((ext_vector_type(4))) float f32x4;
typedef __attribute__((ext_vector_type(8))) short bf16x8;
typedef __attribute__((ext_vector_type(4))) short bf16x4;

constexpr int Bc = 4, Lc = 2048, Sc = 2048, Dc = 1024, Hc = 8, Ec = 128, UVc = 128;
constexpr int HEc = Hc * Ec;   // 1024
constexpr int BLc = Bc * Lc;   // 8192

DEVI unsigned f2bf_bits(float f) {
  unsigned u = __builtin_bit_cast(unsigned, f);
  return (u + 0x7FFFu + ((u >> 16) & 1u)) >> 16;
}
DEVI short f2bf(float f) { return (short)f2bf_bits(f); }
DEVI float bf2f(short s) {
  return __builtin_bit_cast(float, (unsigned)((unsigned short)s) << 16);
}
DEVI float gelu_f(float x) { return 0.5f * x * (1.0f + erff(x * 0.7071067811865476f)); }

DEVI void gload16(const void* gsrc, void* ldst) {
  __builtin_amdgcn_global_load_lds(
      (const __attribute__((address_space(1))) unsigned*)gsrc,
      (__attribute__((address_space(3))) unsigned*)(ldst), 16, 0, 0);
}

DEVI f32x4 mfma16(bf16x8 a, bf16x8 b, f32x4 c) {
  return __builtin_amdgcn_mfma_f32_16x16x32_bf16(a, b, c, 0, 0, 0);
}

// ---------------- prep: f32 -> bf16 convert (8 elems/thread) ----------------
__global__ void cvt_bf16_kernel(const float* __restrict__ in, short* __restrict__ out) {
  size_t i = ((size_t)blockIdx.x * 256 + threadIdx.x) * 8;
  float4 f1 = *reinterpret_cast<const float4*>(in + i);
  float4 f2 = *reinterpret_cast<const float4*>(in + i + 4);
  uint4 pk;
  pk.x = f2bf_bits(f1.x) | (f2bf_bits(f1.y) << 16);
  pk.y = f2bf_bits(f1.z) | (f2bf_bits(f1.w) << 16);
  pk.z = f2bf_bits(f2.x) | (f2bf_bits(f2.y) << 16);
  pk.w = f2bf_bits(f2.z) | (f2bf_bits(f2.w) << 16);
  *reinterpret_cast<uint4*>(out + i) = pk;
}

// ---------------- prep: 4 weight transposes f32[K][N] -> bf16 WT[N][K] ----------------
__global__ void wt_trans_kernel(const float* __restrict__ W0, const float* __restrict__ W1,
                                const float* __restrict__ W2, const float* __restrict__ W3,
                                short* __restrict__ T0, short* __restrict__ T1,
                                short* __restrict__ T2, short* __restrict__ T3) {
  __shared__ float t[32][33];
  const float* Ws[4] = {W0, W1, W2, W3};
  short* Ts[4] = {T0, T1, T2, T3};
  const float* W = Ws[blockIdx.z];
  short* WT = Ts[blockIdx.z];
  int tx = threadIdx.x, ty = threadIdx.y;
  int n0 = blockIdx.x * 32, k0 = blockIdx.y * 32;
#pragma unroll
  for (int i = 0; i < 4; i++) {
    int r = ty + i * 8;
    t[r][tx] = W[(size_t)(k0 + r) * 1024 + n0 + tx];
  }
  __syncthreads();
#pragma unroll
  for (int i = 0; i < 4; i++) {
    int r = ty + i * 8;
    WT[(size_t)(n0 + r) * 1024 + k0 + tx] = f2bf(t[tx][r]);
  }
}

// ---------------- prep: packed rope table [2048][512] of (cos,sin) ----------------
__global__ void rope_cs_kernel(float2* __restrict__ cs) {
  int idx = blockIdx.x * 256 + threadIdx.x;  // 1M
  int t = idx >> 9, i = idx & 511;
  float inv = expf((float)i * (-9.210340371976184f / 512.0f));  // 10000^(-i/512)
  float sv, cv;
  sincosf((float)t * inv, &sv, &cv);
  cs[idx] = make_float2(cv, sv);
}

// ---------------- GEMM: C = epi(A @ W + bias); A bf16 [M][K], W as WT[N][K] bf16 ----------
// 128x128 tile, BK=32, 3-buffer LDS pipeline (counted vmcnt, 1 barrier/step).
// EPI: 0 = f32+bias, 1 = gelu->bf16, 3 = gelu->bf16 written transposed to vT layout.
template <int EPI>
__global__ __launch_bounds__(256, 3) void gemm_kernel(
    const short* __restrict__ A, const short* __restrict__ BT,
    const float* __restrict__ bias, void* __restrict__ Cptr, int M, int N, int K) {
  __shared__ char smem[49152];  // A bufs 3x8K @0, B bufs 3x8K @24K
  const int tid = threadIdx.x;
  const int wave = tid >> 6, lane = tid & 63;
  const int lquad = lane >> 4, l15 = lane & 15;
  const int m0 = blockIdx.x * 128, n0 = blockIdx.y * 128;
  const int wr = wave >> 1, wc = wave & 1;
  f32x4 acc[4][4] = {};

  const int q0 = tid * 16, q1 = tid * 16 + 4096;
  const int r0 = q0 >> 6, o0 = (q0 & 63) ^ ((r0 & 3) << 4);
  const int r1 = q1 >> 6, o1 = (q1 & 63) ^ ((r1 & 3) << 4);
  const short* a0 = A + (size_t)(m0 + r0) * K + (o0 >> 1);
  const short* a1 = A + (size_t)(m0 + r1) * K + (o1 >> 1);
  const short* b0 = BT + (size_t)(n0 + r0) * K + (o0 >> 1);
  const short* b1 = BT + (size_t)(n0 + r1) * K + (o1 >> 1);

#define G_STAGE(buf, kt)                     \
  {                                          \
    char* As_ = smem + (buf)*8192;           \
    char* Bs_ = smem + 24576 + (buf)*8192;   \
    gload16(a0 + (kt), As_ + q0);            \
    gload16(a1 + (kt), As_ + q1);            \
    gload16(b0 + (kt), Bs_ + q0);            \
    gload16(b1 + (kt), Bs_ + q1);            \
  }

  G_STAGE(0, 0);
  G_STAGE(1, 32);
  asm volatile("s_waitcnt vmcnt(4)" ::: "memory");
  __builtin_amdgcn_s_barrier();

  const int NT = K >> 5;
  int cur = 0;
  for (int t = 0; t < NT; t++) {
    int nb = cur + 2;
    if (nb >= 3) nb -= 3;
    G_STAGE(nb, (t + 2 < NT) ? (t + 2) * 32 : 0);  // dummy tail keeps vmcnt math uniform
    __builtin_amdgcn_sched_barrier(0);
    const char* As_ = smem + cur * 8192;
    const char* Bs_ = smem + 24576 + cur * 8192;
    const int ko = lquad * 16;
    bf16x8 a[4], b[4];
#pragma unroll
    for (int f = 0; f < 4; f++) {
      int ra = wr * 64 + f * 16 + l15;
      a[f] = *reinterpret_cast<const bf16x8*>(As_ + ra * 64 + (ko ^ ((ra & 3) << 4)));
      int rb = wc * 64 + f * 16 + l15;
      b[f] = *reinterpret_cast<const bf16x8*>(Bs_ + rb * 64 + (ko ^ ((rb & 3) << 4)));
    }
#pragma unroll
    for (int mf = 0; mf < 4; mf++)
#pragma unroll
      for (int nf = 0; nf < 4; nf++)
        acc[mf][nf] = mfma16(a[mf], b[nf], acc[mf][nf]);
    asm volatile("s_waitcnt vmcnt(4) lgkmcnt(0)" ::: "memory");
    __builtin_amdgcn_sched_barrier(0);
    __builtin_amdgcn_s_barrier();
    cur = (cur == 2) ? 0 : cur + 1;
  }
#undef G_STAGE

#pragma unroll
  for (int mf = 0; mf < 4; mf++) {
#pragma unroll
    for (int nf = 0; nf < 4; nf++) {
      const int mrow = m0 + wr * 64 + mf * 16 + 4 * lquad;
      const int ncol = n0 + wc * 64 + nf * 16 + l15;
      const float bval = bias[ncol];
      if constexpr (EPI == 3) {
        // transposed V write: vT[((b*8+h)*128+d)*2048 + s], s = 4 consecutive (over r)
        int hh = ncol >> 7, dd = ncol & 127;
        int bb = mrow >> 11, ss = mrow & 2047;
        bf16x4 gv;
#pragma unroll
        for (int r = 0; r < 4; r++) gv[r] = f2bf(gelu_f(acc[mf][nf][r] + bval));
        *reinterpret_cast<bf16x4*>((short*)Cptr + (((size_t)bb * 8 + hh) * 128 + dd) * 2048 + ss) = gv;
      } else if constexpr (EPI == 1) {
#pragma unroll
        for (int r = 0; r < 4; r++)
          ((short*)Cptr)[(size_t)(mrow + r) * N + ncol] = f2bf(gelu_f(acc[mf][nf][r] + bval));
      } else {
#pragma unroll
        for (int r = 0; r < 4; r++)
          ((float*)Cptr)[(size_t)(mrow + r) * N + ncol] = acc[mf][nf][r] + bval;
      }
    }
  }
}

// ---------------- rope apply: qk_gelu -> q, k ----------------
__global__ void rope_apply_kernel(const short* __restrict__ qkg,
                                  const float2* __restrict__ cstab,
                                  const float* __restrict__ qg, const float* __restrict__ qb,
                                  const float* __restrict__ kg, const float* __restrict__ kb,
                                  short* __restrict__ qo, short* __restrict__ ko) {
  int tid = blockIdx.x * 256 + threadIdx.x;
  size_t base = (size_t)tid * 8;
  int bl = (int)(base >> 10);
  int rem = (int)(base & 1023);
  int e0 = rem & 127;
  int t = bl & 2047;
  int pf = rem >> 1;  // flat pair index
  uint4 raw = *reinterpret_cast<const uint4*>(qkg + base);
  short sh[8];
  *reinterpret_cast<uint4*>(sh) = raw;
  const float* csf = (const float*)cstab + (size_t)t * 1024 + 2 * pf;
  float4 p01 = *reinterpret_cast<const float4*>(csf);
  float4 p23 = *reinterpret_cast<const float4*>(csf + 4);
  float C[4] = {p01.x, p01.z, p23.x, p23.z};
  float Sn[4] = {p01.y, p01.w, p23.y, p23.w};
  float4 qga = *reinterpret_cast<const float4*>(qg + e0);
  float4 qgb = *reinterpret_cast<const float4*>(qg + e0 + 4);
  float4 qba = *reinterpret_cast<const float4*>(qb + e0);
  float4 qbb = *reinterpret_cast<const float4*>(qb + e0 + 4);
  float4 kga = *reinterpret_cast<const float4*>(kg + e0);
  float4 kgb = *reinterpret_cast<const float4*>(kg + e0 + 4);
  float4 kba = *reinterpret_cast<const float4*>(kb + e0);
  float4 kbb = *reinterpret_cast<const float4*>(kb + e0 + 4);
  float QG[8] = {qga.x, qga.y, qga.z, qga.w, qgb.x, qgb.y, qgb.z, qgb.w};
  float QB[8] = {qba.x, qba.y, qba.z, qba.w, qbb.x, qbb.y, qbb.z, qbb.w};
  float KG[8] = {kga.x, kga.y, kga.z, kga.w, kgb.x, kgb.y, kgb.z, kgb.w};
  float KB[8] = {kba.x, kba.y, kba.z, kba.w, kbb.x, kbb.y, kbb.z, kbb.w};
  short qsh[8], ksh[8];
#pragma unroll
  for (int j = 0; j < 4; j++) {
    float x0 = bf2f(sh[2 * j]), x1 = bf2f(sh[2 * j + 1]);
    float q0 = x0 * QG[2 * j] + QB[2 * j];
    float q1 = x1 * QG[2 * j + 1] + QB[2 * j + 1];
    qsh[2 * j] = f2bf(q0 * C[j] - q1 * Sn[j]);
    qsh[2 * j + 1] = f2bf(q1 * C[j] + q0 * Sn[j]);
    float k0v = x0 * KG[2 * j] + KB[2 * j];
    float k1v = x1 * KG[2 * j + 1] + KB[2 * j + 1];
    ksh[2 * j] = f2bf(k0v * C[j] - k1v * Sn[j]);
    ksh[2 * j + 1] = f2bf(k1v * C[j] + k0v * Sn[j]);
  }
  *reinterpret_cast<uint4*>(qo + base) = *reinterpret_cast<uint4*>(qsh);
  *reinterpret_cast<uint4*>(ko + base) = *reinterpret_cast<uint4*>(ksh);
}

// ---------------- attention ----------------
// grid 1024 = 8 XCD * 4 bh * 32 lblk; per block 64 L-rows (16/wave).
// Pass A: s-tile 64, 3x16K K bufs, vmcnt(4). Pass B: s-tile 32, 3x(K 8K + V 8K), vmcnt(6).
__global__ __launch_bounds__(256, 3) void attn_kernel(
    const short* __restrict__ qs, const short* __restrict__ ks,
    const short* __restrict__ vT, const short* __restrict__ up,
    float* __restrict__ attn_out, short* __restrict__ gate) {
  __shared__ char smem[49152];
  const int bid = blockIdx.x;
  const int xcd = bid & 7, jj = bid >> 3;  // jj 0..127
  const int bh = xcd * 4 + (jj >> 5);
  const int lblk = jj & 31;
  const int b = bh >> 3, h = bh & 7;
  const int l0 = lblk * 64;
  const int tid = threadIdx.x;
  const int wave = tid >> 6, lane = tid & 63;
  const int lquad = lane >> 4, l15 = lane & 15;
  const float scale = 0.08838834764831845f;  // 1/sqrt(128)

  // K staging: tile rows of 256B, XOR swizzle ((row&7)<<4); 16B per lane per instr
  const short* ksrc[4];
  int kq[4];
#pragma unroll
  for (int i = 0; i < 4; i++) {
    int q = i * 4096 + tid * 16;
    kq[i] = q;
    int row = q >> 8, off = (q & 255) ^ ((row & 7) << 4);
    ksrc[i] = ks + (((size_t)b * Sc + row) * Hc + h) * Ec + (off >> 1);
  }
  // V staging: tile [128][32] bf16, 64B rows, additive chunk rotation (16B chunks)
  const short* vsrc[2];
  int vq[2];
#pragma unroll
  for (int i = 0; i < 2; i++) {
    int q = i * 4096 + tid * 16;
    vq[i] = q;
    int rv = q >> 6;
    int j = (q >> 4) & 3;
    int c = (j - (rv & 3)) & 3;
    vsrc[i] = vT + ((size_t)bh * UVc + rv) * Sc + (c << 3);
  }

  // Q fragments (B-operand, contiguous-k convention)
  bf16x8 qf[4];
  {
    int lrow = l0 + wave * 16 + l15;
    const short* qp = qs + (((size_t)b * Lc + lrow) * Hc + h) * Ec;
#pragma unroll
    for (int kt = 0; kt < 4; kt++)
      qf[kt] = *reinterpret_cast<const bf16x8*>(qp + kt * 32 + lquad * 8);
  }
  __builtin_amdgcn_sched_barrier(0);

#define STAGE_A(buf, s0)                                  \
  {                                                       \
    char* Kb_ = smem + (buf)*16384;                       \
    gload16(ksrc[0] + (size_t)(s0)*1024, Kb_ + kq[0]);    \
    gload16(ksrc[1] + (size_t)(s0)*1024, Kb_ + kq[1]);    \
    gload16(ksrc[2] + (size_t)(s0)*1024, Kb_ + kq[2]);    \
    gload16(ksrc[3] + (size_t)(s0)*1024, Kb_ + kq[3]);    \
  }

  // ---- pass A: row sums of exp(scale * scores) ----
  STAGE_A(0, 0);
  STAGE_A(1, 64);
  asm volatile("s_waitcnt vmcnt(4)" ::: "memory");
  __builtin_amdgcn_s_barrier();
  float rsa = 0.f, rsb = 0.f;
  int cur = 0;
  for (int t = 0; t < 32; t++) {
    int nb = cur + 2;
    if (nb >= 3) nb -= 3;
    STAGE_A(nb, (t + 2 < 32) ? (t + 2) * 64 : 0);
    __builtin_amdgcn_sched_barrier(0);
    const char* KB_ = smem + cur * 16384;
    f32x4 d[4] = {};
    __builtin_amdgcn_s_setprio(1);
#pragma unroll
    for (int kt = 0; kt < 4; kt++)
#pragma unroll
      for (int sf = 0; sf < 4; sf++) {
        int row = sf * 16 + l15;
        bf16x8 kf = *reinterpret_cast<const bf16x8*>(
            KB_ + row * 256 + ((kt * 64 + lquad * 16) ^ ((row & 7) << 4)));
        d[sf] = mfma16(kf, qf[kt], d[sf]);
      }
    __builtin_amdgcn_s_setprio(0);
#pragma unroll
    for (int sf = 0; sf < 4; sf++)
#pragma unroll
      for (int r = 0; r < 4; r++) {
        float e = __expf(scale * d[sf][r]);
        if (sf & 1) rsb += e; else rsa += e;
      }
    asm volatile("s_waitcnt vmcnt(4) lgkmcnt(0)" ::: "memory");
    __builtin_amdgcn_sched_barrier(0);
    __builtin_amdgcn_s_barrier();
    cur = (cur == 2) ? 0 : cur + 1;
  }
#undef STAGE_A
  float rs = rsa + rsb;
  rs += __shfl_xor(rs, 16);
  rs += __shfl_xor(rs, 32);
  const float rcp = 1.0f / rs;

  // ---- pass B: recompute, write attn (nt), accumulate ctx^T = V^T @ P^T ----
#define STAGE_B(buf, s0)                                  \
  {                                                       \
    char* Kb_ = smem + (buf)*8192;                        \
    char* Vb_ = smem + 24576 + (buf)*8192;                \
    gload16(ksrc[0] + (size_t)(s0)*1024, Kb_ + kq[0]);    \
    gload16(ksrc[1] + (size_t)(s0)*1024, Kb_ + kq[1]);    \
    gload16(vsrc[0] + (s0), Vb_ + vq[0]);                 \
    gload16(vsrc[1] + (s0), Vb_ + vq[1]);                 \
  }

  STAGE_B(0, 0);
  STAGE_B(1, 32);
  asm volatile("s_waitcnt vmcnt(4)" ::: "memory");
  __builtin_amdgcn_s_barrier();
  f32x4 ctx[8] = {};
  cur = 0;
  for (int t = 0; t < 64; t++) {
    const int s0 = t * 32;
    int nb = cur + 2;
    if (nb >= 3) nb -= 3;
    STAGE_B(nb, (t + 2 < 64) ? s0 + 64 : 0);
    __builtin_amdgcn_sched_barrier(0);
    const char* KB_ = smem + cur * 8192;
    const char* VB_ = smem + 24576 + cur * 8192;
    f32x4 d[2] = {};
    __builtin_amdgcn_s_setprio(1);
#pragma unroll
    for (int kt = 0; kt < 4; kt++)
#pragma unroll
      for (int sf = 0; sf < 2; sf++) {
        int row = sf * 16 + l15;
        bf16x8 kf = *reinterpret_cast<const bf16x8*>(
            KB_ + row * 256 + ((kt * 64 + lquad * 16) ^ ((row & 7) << 4)));
        d[sf] = mfma16(kf, qf[kt], d[sf]);
      }
    __builtin_amdgcn_s_setprio(0);
#pragma unroll
    for (int sf = 0; sf < 2; sf++)
#pragma unroll
      for (int r = 0; r < 4; r++)
        d[sf][r] = __expf(scale * d[sf][r]) * rcp;
    {
      int lrow = l0 + wave * 16 + l15;
      float* arow = attn_out + ((size_t)bh * Lc + lrow) * Sc + s0 + lquad * 4;
      __builtin_nontemporal_store(d[0], reinterpret_cast<f32x4*>(arow));
      __builtin_nontemporal_store(d[1], reinterpret_cast<f32x4*>(arow + 16));
    }
    bf16x8 pb;
#pragma unroll
    for (int r = 0; r < 4; r++) {
      pb[r] = f2bf(d[0][r]);
      pb[4 + r] = f2bf(d[1][r]);
    }
    __builtin_amdgcn_s_setprio(1);
#pragma unroll
    for (int df = 0; df < 8; df++) {
      int dd = df * 16 + l15;
      const char* vrow = VB_ + dd * 64;
      int half = (lquad & 1) * 8;
      int clo = ((lquad >> 1) + (dd & 3)) & 3;
      int chi = ((lquad >> 1) + 2 + (dd & 3)) & 3;
      bf16x4 lo = *reinterpret_cast<const bf16x4*>(vrow + clo * 16 + half);
      bf16x4 hi = *reinterpret_cast<const bf16x4*>(vrow + chi * 16 + half);
      bf16x8 vf = __builtin_shufflevector(lo, hi, 0, 1, 2, 3, 4, 5, 6, 7);
      ctx[df] = mfma16(vf, pb, ctx[df]);
    }
    __builtin_amdgcn_s_setprio(0);
    asm volatile("s_waitcnt vmcnt(6) lgkmcnt(0)" ::: "memory");
    __builtin_amdgcn_sched_barrier(0);
    __builtin_amdgcn_s_barrier();
    cur = (cur == 2) ? 0 : cur + 1;
  }
#undef STAGE_B

  // ---- epilogue: gate = u_p * ctx, direct from regs ----
  {
    int lrow = l0 + wave * 16 + l15;
    size_t base = ((size_t)b * Lc + lrow) * HEc + h * UVc;
    const short* ub = up + base;
    short* gp = gate + base;
#pragma unroll
    for (int df = 0; df < 8; df++) {
      int doff = df * 16 + lquad * 4;
      bf16x4 uv = *reinterpret_cast<const bf16x4*>(ub + doff);
      bf16x4 gv;
#pragma unroll
      for (int r = 0; r < 4; r++)
        gv[r] = f2bf(bf2f(uv[r]) * ctx[df][r]);
      *reinterpret_cast<bf16x4*>(gp + doff) = gv;
    }
  }
}

// ---------------- launch ----------------
extern "C" void kernel_launch(void* const* d_in, const int* in_sizes, int n_in,
                              void* d_out, int out_size, void* d_ws, size_t ws_size,
                              hipStream_t stream) {
  const float* u_in = (const float*)d_in[0];
  const float* qry = (const float*)d_in[1];
  // d_in[2] = keys : unused (use_aff shared qk projection)
  const float* vals = (const float*)d_in[3];
  const float* Wqk = (const float*)d_in[4];
  const float* bqk = (const float*)d_in[5];
  const float* Wv = (const float*)d_in[6];
  const float* bv = (const float*)d_in[7];
  const float* Wu = (const float*)d_in[8];
  const float* bu = (const float*)d_in[9];
  const float* Wo = (const float*)d_in[10];
  const float* bo = (const float*)d_in[11];
  const float* qg = (const float*)d_in[12];
  const float* qb = (const float*)d_in[13];
  const float* kg = (const float*)d_in[14];
  const float* kb = (const float*)d_in[15];

  char* w = (char*)d_ws;
  short* WT0 = (short*)w; w += (size_t)1024 * 1024 * 2;
  short* WT1 = (short*)w; w += (size_t)1024 * 1024 * 2;
  short* WT2 = (short*)w; w += (size_t)1024 * 1024 * 2;
  short* WT3 = (short*)w; w += (size_t)1024 * 1024 * 2;
  float2* cstab = (float2*)w; w += (size_t)2048 * 512 * 8;
  const size_t BUF = (size_t)BLc * HEc * 2;  // 16.78 MB
  short* C1 = (short*)w; w += BUF;   // bf16 queries; reused as gate after gemm1
  short* C2 = (short*)w; w += BUF;   // bf16 values
  short* C3 = (short*)w; w += BUF;   // bf16 u
  short* qkg = (short*)w; w += BUF;  // qk gelu out; kbf aliases it (in-place rope)
  short* qbf = (short*)w; w += BUF;
  short* vTb = (short*)w; w += BUF;
  short* upb = (short*)w; w += BUF;
  short* kbf = qkg;  // in-place: rope_apply reads/writes identical indices
  short* gtb = C1;   // C1 dead after gemm1

  float* o_out = (float*)d_out;
  float* attn_out = o_out + (size_t)BLc * Dc;

  dim3 tb(32, 8);
  cvt_bf16_kernel<<<4096, 256, 0, stream>>>(qry, C1);
  cvt_bf16_kernel<<<4096, 256, 0, stream>>>(vals, C2);
  cvt_bf16_kernel<<<4096, 256, 0, stream>>>(u_in, C3);
  wt_trans_kernel<<<dim3(32, 32, 4), tb, 0, stream>>>(Wqk, Wv, Wu, Wo, WT0, WT1, WT2, WT3);
  rope_cs_kernel<<<4096, 256, 0, stream>>>(cstab);

  gemm_kernel<1><<<dim3(64, 8), 256, 0, stream>>>(C1, WT0, bqk, qkg, BLc, HEc, Dc);
  rope_apply_kernel<<<4096, 256, 0, stream>>>(qkg, cstab, qg, qb, kg, kb, qbf, kbf);
  gemm_kernel<3><<<dim3(64, 8), 256, 0, stream>>>(C2, WT1, bv, vTb, BLc, HEc, Dc);
  gemm_kernel<1><<<dim3(64, 8), 256, 0, stream>>>(C3, WT2, bu, upb, BLc, HEc, Dc);
  attn_kernel<<<1024, 256, 0, stream>>>(qbf, kbf, vTb, upb, attn_out, gtb);
  gemm_kernel<0><<<dim3(64, 8), 256, 0, stream>>>(gtb, WT3, bo, o_out, BLc, Dc, HEc);
}